// Round 4
// baseline (421.113 us; speedup 1.0000x reference)
//
#include <hip/hip_runtime.h>
#include <hip/hip_bf16.h>
#include <math.h>

#define NS 16
#define H  48
#define NBLK 768          // 3 blocks/CU x 256 CUs

typedef __attribute__((ext_vector_type(8))) short bf16x8;
typedef __attribute__((ext_vector_type(4))) float f32x4;

// ---- LDS layout (halfword offsets unless noted) ----
// [0,2304)        W1T  [48 out][48 in]   stride 48
// [2304,17664)    W2T  [320 out][48 in]  stride 48
// [17664,17672)   zero block (16 B)
// [17680,23824)   slots: 4 waves x 2 bufs x [16][48]
// bytes [47648,47840)  b1F float[48]
// bytes [47840,49120)  b2F float[320]
// [24560,25584) hw     sX: 4 waves x [16 edges][16] bf16
// bytes [51168,52192)  sV: 4 waves x [16][4] f32 (shx,shy,shz,src-bits)
#define W1O   0
#define W2O   2304
#define ZOFF  17664
#define SLOT0 17680
#define B1F   11912      // float index
#define B2F   11960      // float index
#define SXO   24560      // hw index
#define SVF   12792      // float index
#define SMEM_HW 26096    // 52192 bytes

__device__ __forceinline__ short f2bf(float f) {
    unsigned b = __float_as_uint(f);
    unsigned r = (b + 0x7FFFu + ((b >> 16) & 1u)) >> 16;
    return (short)r;
}
__device__ __forceinline__ float bf2f(short s) {
    return __uint_as_float(((unsigned)(unsigned short)s) << 16);
}

template<bool SLOT>
__global__ __launch_bounds__(256, 3) void edge_mfma_kernel(
    const float* __restrict__ node_attr,
    const float* __restrict__ edge_attr,
    const float* __restrict__ edge_vec,
    const float* __restrict__ fc1_w,
    const float* __restrict__ fc1_b,
    const float* __restrict__ fc2_w,
    const float* __restrict__ fc2_b,
    const int*   __restrict__ edge_index,
    float* __restrict__ dst_buf,   // SLOT ? msg[E][28] : out[N][28]
    float* __restrict__ cnt,       // !SLOT only
    int*   __restrict__ cursor,    // SLOT only
    int E, int MT)
{
    __shared__ __align__(16) short smemS[SMEM_HW];
    float* smemF = (float*)smemS;
    const int tid = threadIdx.x;

    // ---- one-time weight staging ----
    for (int idx = tid; idx < 48 * 48; idx += 256) {
        int n = idx % 48, j = idx / 48;                  // coalesced read
        smemS[W1O + n * 48 + j] = f2bf(fc1_w[j * 48 + n]);
    }
    for (int idx = tid; idx < 320 * 48; idx += 256) {
        int n = idx % 320, j = idx / 320;                // coalesced read
        smemS[W2O + n * 48 + j] = f2bf(fc2_w[j * 320 + n]);
    }
    if (tid < 48) smemF[B1F + tid] = fc1_b[tid];
    for (int idx = tid; idx < 320; idx += 256) smemF[B2F + idx] = fc2_b[idx];
    if (tid < 8) smemS[ZOFF + tid] = 0;
    __syncthreads();
    // All mutable LDS below is wave-private: no further barriers.

    const int l  = tid & 63;
    const int wv = tid >> 6;
    const int g  = l >> 4;
    const int c  = l & 15;
    const int r  = l >> 2;      // staging: edge-in-tile
    const int q  = l & 3;       // staging: quarter

    const int NW = NBLK * 4;
    const int SLW = SLOT0 + wv * 1536;
    const int SXB = SXO + wv * 256;
    const int SVB = SVF + wv * 64;

    int m = blockIdx.x * 4 + wv;
    bool have = (m < MT);
    int p = 0;

    // ---- prologue: load + stage tile m into buf 0 ----
    if (have) {
        int en = m * 16 + r;
        int ce = en < E ? en : (E - 1);
        int sI = edge_index[ce], dI = edge_index[E + ce];
        const float* ap = edge_attr + (size_t)ce * H + q * 12;
        float4 A0 = *(const float4*)ap;
        float4 A1 = *(const float4*)(ap + 4);
        float4 A2 = *(const float4*)(ap + 8);
        float4 X  = *(const float4*)(node_attr + (size_t)dI * NS + q * 4);
        float vx = edge_vec[3 * (size_t)ce + 0];
        float vy = edge_vec[3 * (size_t)ce + 1];
        float vz = edge_vec[3 * (size_t)ce + 2];
        if (en >= E) {
            A0 = make_float4(0,0,0,0); A1 = A0; A2 = A0; X = A0;
            vx = vy = vz = 0.f; sI = 0;
        }
        int b = SLW + r * 48 + q * 12;
        *(short4*)&smemS[b + 0] = make_short4(f2bf(A0.x), f2bf(A0.y), f2bf(A0.z), f2bf(A0.w));
        *(short4*)&smemS[b + 4] = make_short4(f2bf(A1.x), f2bf(A1.y), f2bf(A1.z), f2bf(A1.w));
        *(short4*)&smemS[b + 8] = make_short4(f2bf(A2.x), f2bf(A2.y), f2bf(A2.z), f2bf(A2.w));
        *(short4*)&smemS[SXB + r * 16 + q * 4] =
            make_short4(f2bf(X.x), f2bf(X.y), f2bf(X.z), f2bf(X.w));
        if (q == 0) {
            float rn = 1.0f / (sqrtf(vx*vx + vy*vy + vz*vz) + 1e-8f);
            const float c1 = 1.7320508075688772f;
            float4 sv = make_float4(c1*vx*rn, c1*vy*rn, c1*vz*rn, __int_as_float(sI));
            *(float4*)&smemF[SVB + r * 4] = sv;
        }
    }

    while (have) {
        const int mn = m + NW;
        const bool haven = (mn < MT);
        const int ebase = m * 16;
        const int SLB = SLW + p * 768;

        // ---- issue next tile's independent loads (idx + edge_attr) ----
        int nsI = 0, ndI = 0, nen = 0;
        float4 A0, A1, A2;
        if (haven) {
            nen = mn * 16 + r;
            int ce = nen < E ? nen : (E - 1);
            nsI = edge_index[ce]; ndI = edge_index[E + ce];
            const float* ap = edge_attr + (size_t)ce * H + q * 12;
            A0 = *(const float4*)ap;
            A1 = *(const float4*)(ap + 4);
            A2 = *(const float4*)(ap + 8);
        }

        // ---- GEMM1 on buf[p] ----
        bf16x8 a0 = *(const bf16x8*)&smemS[SLB + c * 48 + g * 8];
        int a1o = (g < 2) ? (SLB + c * 48 + 32 + g * 8) : ZOFF;
        bf16x8 a1 = *(const bf16x8*)&smemS[a1o];
        #pragma unroll
        for (int fr = 0; fr < 3; ++fr) {
            bf16x8 b0 = *(const bf16x8*)&smemS[W1O + (fr*16 + c) * 48 + g * 8];
            int b1o = (g < 2) ? (W1O + (fr*16 + c) * 48 + 32 + g * 8) : ZOFF;
            bf16x8 b1 = *(const bf16x8*)&smemS[b1o];
            f32x4 acc = {0.f, 0.f, 0.f, 0.f};
            acc = __builtin_amdgcn_mfma_f32_16x16x32_bf16(a0, b0, acc, 0, 0, 0);
            acc = __builtin_amdgcn_mfma_f32_16x16x32_bf16(a1, b1, acc, 0, 0, 0);
            float bia = smemF[B1F + fr * 16 + c];
            #pragma unroll
            for (int j = 0; j < 4; ++j)
                smemS[SLB + (g*4 + j) * 48 + fr * 16 + c] =
                    f2bf(fmaxf(acc[j] + bia, 0.f));
        }

        // ---- dependent chase for next tile (idx has returned by now) ----
        float4 X; float vx = 0, vy = 0, vz = 0;
        if (haven) {
            X = *(const float4*)(node_attr + (size_t)ndI * NS + q * 4);
            int ce = nen < E ? nen : (E - 1);
            vx = edge_vec[3 * (size_t)ce + 0];
            vy = edge_vec[3 * (size_t)ce + 1];
            vz = edge_vec[3 * (size_t)ce + 2];
        }

        // ---- t-fragments + x registers ----
        bf16x8 t0 = *(const bf16x8*)&smemS[SLB + c * 48 + g * 8];
        int t1o = (g < 2) ? (SLB + c * 48 + 32 + g * 8) : ZOFF;
        bf16x8 t1 = *(const bf16x8*)&smemS[t1o];
        bf16x8 xr0[4], xr1[4];
        #pragma unroll
        for (int j = 0; j < 4; ++j) {
            xr0[j] = *(const bf16x8*)&smemS[SXB + (g*4 + j) * 16];
            xr1[j] = *(const bf16x8*)&smemS[SXB + (g*4 + j) * 16 + 8];
        }

        // ---- GEMM2 + fused contraction ----
        float o0[4] = {0.f, 0.f, 0.f, 0.f};
        float o1[4] = {0.f, 0.f, 0.f, 0.f};
        #pragma unroll
        for (int u = 0; u < 16; ++u) {
            int rw = u * 16 + c;
            bf16x8 b0 = *(const bf16x8*)&smemS[W2O + rw * 48 + g * 8];
            int b1o = (g < 2) ? (W2O + rw * 48 + 32 + g * 8) : ZOFF;
            bf16x8 b1 = *(const bf16x8*)&smemS[b1o];
            f32x4 acc = {0.f, 0.f, 0.f, 0.f};
            acc = __builtin_amdgcn_mfma_f32_16x16x32_bf16(t0, b0, acc, 0, 0, 0);
            acc = __builtin_amdgcn_mfma_f32_16x16x32_bf16(t1, b1, acc, 0, 0, 0);
            float bia = smemF[B2F + rw];
            #pragma unroll
            for (int j = 0; j < 4; ++j) {
                float xu = bf2f(u < 8 ? xr0[j][u] : xr1[j][u - 8]);
                o0[j] = fmaf(xu, acc[j] + bia, o0[j]);
            }
        }
        const int s2 = c >> 2;
        #pragma unroll
        for (int f = 0; f < 4; ++f) {
            int rw = 256 + f * 16 + c;
            bf16x8 b0 = *(const bf16x8*)&smemS[W2O + rw * 48 + g * 8];
            int b1o = (g < 2) ? (W2O + rw * 48 + 32 + g * 8) : ZOFF;
            bf16x8 b1 = *(const bf16x8*)&smemS[b1o];
            f32x4 acc = {0.f, 0.f, 0.f, 0.f};
            acc = __builtin_amdgcn_mfma_f32_16x16x32_bf16(t0, b0, acc, 0, 0, 0);
            acc = __builtin_amdgcn_mfma_f32_16x16x32_bf16(t1, b1, acc, 0, 0, 0);
            float bia = smemF[B2F + rw];
            #pragma unroll
            for (int j = 0; j < 4; ++j) {
                float e0, e1, e2, e3;
                if (f < 2) {
                    e0 = bf2f(xr0[j][f*4+0]); e1 = bf2f(xr0[j][f*4+1]);
                    e2 = bf2f(xr0[j][f*4+2]); e3 = bf2f(xr0[j][f*4+3]);
                } else {
                    e0 = bf2f(xr1[j][(f-2)*4+0]); e1 = bf2f(xr1[j][(f-2)*4+1]);
                    e2 = bf2f(xr1[j][(f-2)*4+2]); e3 = bf2f(xr1[j][(f-2)*4+3]);
                }
                float xu = e0;
                xu = (s2 == 1) ? e1 : xu;
                xu = (s2 == 2) ? e2 : xu;
                xu = (s2 == 3) ? e3 : xu;
                o1[j] = fmaf(xu, acc[j] + bia, o1[j]);
            }
        }
        #pragma unroll
        for (int j = 0; j < 4; ++j) {
            o1[j] += __shfl_xor(o1[j], 4);
            o1[j] += __shfl_xor(o1[j], 8);
        }

        // ---- epilogue ----
        const float inv = 0.25f;
        #pragma unroll
        for (int j = 0; j < 4; ++j) {
            int e = ebase + g * 4 + j;
            float4 sv = *(const float4*)&smemF[SVB + (g*4 + j) * 4];
            int srcn = __float_as_int(sv.w);
            if constexpr (SLOT) {
                int pos = 0;
                if (c == j && e < E) pos = atomicAdd(cursor + srcn, 1);
                int slot = __shfl(pos, (g << 4) + j);
                if (e < E) {
                    float* mb = dst_buf + (size_t)slot * 28;
                    mb[c] = o0[j] * inv;
                    if (c < 4) {
                        float qq = o1[j] * inv;
                        mb[16 + 3*c + 0] = qq * sv.x;
                        mb[16 + 3*c + 1] = qq * sv.y;
                        mb[16 + 3*c + 2] = qq * sv.z;
                    }
                }
            } else {
                if (e < E) {
                    float* ob = dst_buf + (size_t)srcn * 28;
                    atomicAdd(ob + c, o0[j] * inv);
                    if (c < 4) {
                        float qq = o1[j] * inv;
                        atomicAdd(ob + 16 + 3*c + 0, qq * sv.x);
                        atomicAdd(ob + 16 + 3*c + 1, qq * sv.y);
                        atomicAdd(ob + 16 + 3*c + 2, qq * sv.z);
                    }
                    if (c == 0) atomicAdd(cnt + srcn, 1.0f);
                }
            }
        }

        // ---- stage next tile into buf[p^1] + sX/sV ----
        if (haven) {
            if (nen >= E) {
                A0 = make_float4(0,0,0,0); A1 = A0; A2 = A0; X = A0;
                vx = vy = vz = 0.f; nsI = 0;
            }
            int b = SLW + (p ^ 1) * 768 + r * 48 + q * 12;
            *(short4*)&smemS[b + 0] = make_short4(f2bf(A0.x), f2bf(A0.y), f2bf(A0.z), f2bf(A0.w));
            *(short4*)&smemS[b + 4] = make_short4(f2bf(A1.x), f2bf(A1.y), f2bf(A1.z), f2bf(A1.w));
            *(short4*)&smemS[b + 8] = make_short4(f2bf(A2.x), f2bf(A2.y), f2bf(A2.z), f2bf(A2.w));
            *(short4*)&smemS[SXB + r * 16 + q * 4] =
                make_short4(f2bf(X.x), f2bf(X.y), f2bf(X.z), f2bf(X.w));
            if (q == 0) {
                float rn = 1.0f / (sqrtf(vx*vx + vy*vy + vz*vz) + 1e-8f);
                const float c1 = 1.7320508075688772f;
                float4 sv = make_float4(c1*vx*rn, c1*vy*rn, c1*vz*rn, __int_as_float(nsI));
                *(float4*)&smemF[SVB + r * 4] = sv;
            }
        }
        m = mn; have = haven; p ^= 1;
    }
}

__global__ __launch_bounds__(256) void hist_kernel(
    const int* __restrict__ edge_index, int* __restrict__ deg, int E)
{
    int i = blockIdx.x * blockDim.x + threadIdx.x;
    if (i < E) atomicAdd(deg + edge_index[i], 1);
}

__global__ __launch_bounds__(1024) void scan_kernel(
    const int* __restrict__ deg, int* __restrict__ starts,
    int* __restrict__ cursor, int N)
{
    __shared__ int lds[1024];
    int t = threadIdx.x;
    int chunk = (N + 1023) / 1024;
    int lo = t * chunk;
    int hi = lo + chunk; if (hi > N) hi = N;
    int s = 0;
    for (int i = lo; i < hi; ++i) s += deg[i];
    lds[t] = s;
    __syncthreads();
    int v = s;
    for (int off = 1; off < 1024; off <<= 1) {
        int u = (t >= off) ? lds[t - off] : 0;
        __syncthreads();
        v += u;
        lds[t] = v;
        __syncthreads();
    }
    int run = v - s;
    for (int i = lo; i < hi; ++i) {
        starts[i] = run;
        cursor[i] = run;
        run += deg[i];
    }
}

__global__ __launch_bounds__(256) void sum_kernel(
    const float* __restrict__ msg, const int* __restrict__ starts,
    const int* __restrict__ deg, float* __restrict__ out, int N)
{
    int wvid = (blockIdx.x * blockDim.x + threadIdx.x) >> 5;
    int ch = threadIdx.x & 31;
    int n = wvid;
    if (n < N && ch < 28) {
        int s = starts[n];
        int d = deg[n];
        float acc = 0.f;
        for (int k = 0; k < d; ++k)
            acc += msg[(size_t)(s + k) * 28 + ch];
        out[(size_t)n * 28 + ch] = acc / fmaxf((float)d, 1.0f);
    }
}

__global__ __launch_bounds__(256) void finalize_kernel(
    float* __restrict__ out, const float* __restrict__ cnt, int total)
{
    int i = blockIdx.x * blockDim.x + threadIdx.x;
    if (i < total) {
        float cv = cnt[i / 28];
        out[i] = out[i] / fmaxf(cv, 1.0f);
    }
}

extern "C" void kernel_launch(void* const* d_in, const int* in_sizes, int n_in,
                              void* d_out, int out_size, void* d_ws, size_t ws_size,
                              hipStream_t stream) {
    const float* node_attr  = (const float*)d_in[0];
    const float* edge_attr  = (const float*)d_in[1];
    const float* edge_vec   = (const float*)d_in[2];
    const float* fc1_w      = (const float*)d_in[3];
    const float* fc1_b      = (const float*)d_in[4];
    const float* fc2_w      = (const float*)d_in[5];
    const float* fc2_b      = (const float*)d_in[6];
    const int*   edge_index = (const int*)d_in[7];

    int E = in_sizes[2] / 3;      // 400000
    int N = in_sizes[0] / NS;     // 50000
    float* out = (float*)d_out;
    int MT = (E + 15) / 16;

    size_t need = ((size_t)E * 28 + 3 * (size_t)N) * sizeof(float);
    if (ws_size >= need) {
        float* msg  = (float*)d_ws;
        int* ip     = (int*)((char*)d_ws + (size_t)E * 28 * sizeof(float));
        int* deg    = ip;
        int* starts = ip + N;
        int* cursor = ip + 2 * N;

        hipMemsetAsync(deg, 0, (size_t)N * sizeof(int), stream);
        hist_kernel<<<(E + 255) / 256, 256, 0, stream>>>(edge_index, deg, E);
        scan_kernel<<<1, 1024, 0, stream>>>(deg, starts, cursor, N);
        edge_mfma_kernel<true><<<NBLK, 256, 0, stream>>>(
            node_attr, edge_attr, edge_vec, fc1_w, fc1_b, fc2_w, fc2_b,
            edge_index, msg, nullptr, cursor, E, MT);
        sum_kernel<<<((size_t)N * 32 + 255) / 256, 256, 0, stream>>>(
            msg, starts, deg, out, N);
    } else {
        float* cnt = (float*)d_ws;
        hipMemsetAsync(d_out, 0, (size_t)out_size * sizeof(float), stream);
        hipMemsetAsync(d_ws, 0, (size_t)N * sizeof(float), stream);
        edge_mfma_kernel<false><<<NBLK, 256, 0, stream>>>(
            node_attr, edge_attr, edge_vec, fc1_w, fc1_b, fc2_w, fc2_b,
            edge_index, out, cnt, nullptr, E, MT);
        int total = N * 28;
        finalize_kernel<<<(total + 255) / 256, 256, 0, stream>>>(out, cnt, total);
    }
}

// Round 5
// 397.286 us; speedup vs baseline: 1.0600x; 1.0600x over previous
//
#include <hip/hip_runtime.h>
#include <hip/hip_bf16.h>
#include <math.h>

#define NS 16
#define H  48
#define NBLK 768          // 3 blocks/CU x 256 CUs

typedef __attribute__((ext_vector_type(8))) short bf16x8;
typedef __attribute__((ext_vector_type(4))) float f32x4;

// ---- LDS layout (halfword offsets unless noted) ----
#define W1O   0          // W1T [48 out][48 in]
#define W2O   2304       // W2T [320 out][48 in]
#define ZOFF  17664      // 16B zero block
#define SLOT0 17680      // 4 waves x 2 bufs x [16][48]
#define B1F   11912      // float idx: fc1_b[48]
#define B2F   11960      // float idx: fc2_b[320]
#define SXO   24560      // hw idx: sX 4 waves x [16][16] bf16
#define SVF   12792      // float idx: sV 4 waves x [16][4]
#define SMEM_HW 26096    // 52192 bytes

__device__ __forceinline__ short f2bf(float f) {
    unsigned b = __float_as_uint(f);
    unsigned r = (b + 0x7FFFu + ((b >> 16) & 1u)) >> 16;
    return (short)r;
}
__device__ __forceinline__ float bf2f(short s) {
    return __uint_as_float(((unsigned)(unsigned short)s) << 16);
}

template<bool SLOT>
__global__ __launch_bounds__(256, 3) void edge_mfma_kernel(
    const float* __restrict__ node_attr,
    const float* __restrict__ edge_attr,
    const float* __restrict__ edge_vec,
    const float* __restrict__ fc1_w,
    const float* __restrict__ fc1_b,
    const float* __restrict__ fc2_w,
    const float* __restrict__ fc2_b,
    const int*   __restrict__ edge_index,
    float* __restrict__ dst_buf,   // SLOT ? msg[E][mstride] : out[N][28]
    float* __restrict__ cnt,       // !SLOT only
    int*   __restrict__ cursor,    // SLOT only
    int E, int MT, int mstride, int pad32)
{
    __shared__ __align__(16) short smemS[SMEM_HW];
    float* smemF = (float*)smemS;
    const int tid = threadIdx.x;

    // ---- one-time weight staging ----
    for (int idx = tid; idx < 48 * 48; idx += 256) {
        int n = idx % 48, j = idx / 48;
        smemS[W1O + n * 48 + j] = f2bf(fc1_w[j * 48 + n]);
    }
    for (int idx = tid; idx < 320 * 48; idx += 256) {
        int n = idx % 320, j = idx / 320;
        smemS[W2O + n * 48 + j] = f2bf(fc2_w[j * 320 + n]);
    }
    if (tid < 48) smemF[B1F + tid] = fc1_b[tid];
    for (int idx = tid; idx < 320; idx += 256) smemF[B2F + idx] = fc2_b[idx];
    if (tid < 8) smemS[ZOFF + tid] = 0;
    __syncthreads();
    // All mutable LDS below is wave-private: no further barriers.

    const int l  = tid & 63;
    const int wv = tid >> 6;
    const int g  = l >> 4;
    const int c  = l & 15;
    const int r  = l >> 2;
    const int q  = l & 3;

    const int NW = NBLK * 4;
    const int SLW = SLOT0 + wv * 1536;
    const int SXB = SXO + wv * 256;
    const int SVB = SVF + wv * 64;

    int m = blockIdx.x * 4 + wv;
    bool have = (m < MT);
    int p = 0;

    // ---- prologue: load + stage tile m into buf 0 ----
    if (have) {
        int en = m * 16 + r;
        int ce = en < E ? en : (E - 1);
        int sI = edge_index[ce], dI = edge_index[E + ce];
        const float* ap = edge_attr + (size_t)ce * H + q * 12;
        float4 A0 = *(const float4*)ap;
        float4 A1 = *(const float4*)(ap + 4);
        float4 A2 = *(const float4*)(ap + 8);
        float4 X  = *(const float4*)(node_attr + (size_t)dI * NS + q * 4);
        if (en >= E) { A0 = make_float4(0,0,0,0); A1 = A0; A2 = A0; X = A0; sI = 0; }
        int b = SLW + r * 48 + q * 12;
        *(short4*)&smemS[b + 0] = make_short4(f2bf(A0.x), f2bf(A0.y), f2bf(A0.z), f2bf(A0.w));
        *(short4*)&smemS[b + 4] = make_short4(f2bf(A1.x), f2bf(A1.y), f2bf(A1.z), f2bf(A1.w));
        *(short4*)&smemS[b + 8] = make_short4(f2bf(A2.x), f2bf(A2.y), f2bf(A2.z), f2bf(A2.w));
        *(short4*)&smemS[SXB + r * 16 + q * 4] =
            make_short4(f2bf(X.x), f2bf(X.y), f2bf(X.z), f2bf(X.w));
        if (q == 0) {
            float vx = 0.f, vy = 0.f, vz = 0.f;
            if (en < E) {
                vx = edge_vec[3 * (size_t)ce + 0];
                vy = edge_vec[3 * (size_t)ce + 1];
                vz = edge_vec[3 * (size_t)ce + 2];
            }
            float rn = 1.0f / (sqrtf(vx*vx + vy*vy + vz*vz) + 1e-8f);
            const float c1 = 1.7320508075688772f;
            float4 sv = make_float4(c1*vx*rn, c1*vy*rn, c1*vz*rn, __int_as_float(sI));
            *(float4*)&smemF[SVB + r * 4] = sv;
        }
    }

    while (have) {
        const int mn = m + NW;
        const bool haven = (mn < MT);
        const int ebase = m * 16;
        const int SLB = SLW + p * 768;

        // ---- issue next tile's independent loads (idx + edge_attr) ----
        int nsI = 0, ndI = 0, nen = 0;
        float4 A0, A1, A2;
        if (haven) {
            nen = mn * 16 + r;
            int ce = nen < E ? nen : (E - 1);
            nsI = edge_index[ce]; ndI = edge_index[E + ce];
            const float* ap = edge_attr + (size_t)ce * H + q * 12;
            A0 = *(const float4*)ap;
            A1 = *(const float4*)(ap + 4);
            A2 = *(const float4*)(ap + 8);
        }

        // ---- GEMM1 on buf[p] ----
        bf16x8 a0 = *(const bf16x8*)&smemS[SLB + c * 48 + g * 8];
        int a1o = (g < 2) ? (SLB + c * 48 + 32 + g * 8) : ZOFF;
        bf16x8 a1 = *(const bf16x8*)&smemS[a1o];
        #pragma unroll
        for (int fr = 0; fr < 3; ++fr) {
            bf16x8 b0 = *(const bf16x8*)&smemS[W1O + (fr*16 + c) * 48 + g * 8];
            int b1o = (g < 2) ? (W1O + (fr*16 + c) * 48 + 32 + g * 8) : ZOFF;
            bf16x8 b1 = *(const bf16x8*)&smemS[b1o];
            f32x4 acc = {0.f, 0.f, 0.f, 0.f};
            acc = __builtin_amdgcn_mfma_f32_16x16x32_bf16(a0, b0, acc, 0, 0, 0);
            acc = __builtin_amdgcn_mfma_f32_16x16x32_bf16(a1, b1, acc, 0, 0, 0);
            float bia = smemF[B1F + fr * 16 + c];
            #pragma unroll
            for (int j = 0; j < 4; ++j)
                smemS[SLB + (g*4 + j) * 48 + fr * 16 + c] =
                    f2bf(fmaxf(acc[j] + bia, 0.f));
        }

        // ---- dependent chase for next tile ----
        float4 X; float vx = 0.f, vy = 0.f, vz = 0.f;
        if (haven) {
            X = *(const float4*)(node_attr + (size_t)ndI * NS + q * 4);
            if (q == 0 && nen < E) {
                int ce = nen;
                vx = edge_vec[3 * (size_t)ce + 0];
                vy = edge_vec[3 * (size_t)ce + 1];
                vz = edge_vec[3 * (size_t)ce + 2];
            }
        }

        // ---- t-fragments + x registers ----
        bf16x8 t0 = *(const bf16x8*)&smemS[SLB + c * 48 + g * 8];
        int t1o = (g < 2) ? (SLB + c * 48 + 32 + g * 8) : ZOFF;
        bf16x8 t1 = *(const bf16x8*)&smemS[t1o];
        bf16x8 xr0[4], xr1[4];
        #pragma unroll
        for (int j = 0; j < 4; ++j) {
            xr0[j] = *(const bf16x8*)&smemS[SXB + (g*4 + j) * 16];
            xr1[j] = *(const bf16x8*)&smemS[SXB + (g*4 + j) * 16 + 8];
        }

        // ---- GEMM2 + fused contraction ----
        float o0[4] = {0.f, 0.f, 0.f, 0.f};
        float o1[4] = {0.f, 0.f, 0.f, 0.f};
        #pragma unroll
        for (int u = 0; u < 16; ++u) {
            int rw = u * 16 + c;
            bf16x8 b0 = *(const bf16x8*)&smemS[W2O + rw * 48 + g * 8];
            int b1o = (g < 2) ? (W2O + rw * 48 + 32 + g * 8) : ZOFF;
            bf16x8 b1 = *(const bf16x8*)&smemS[b1o];
            f32x4 acc = {0.f, 0.f, 0.f, 0.f};
            acc = __builtin_amdgcn_mfma_f32_16x16x32_bf16(t0, b0, acc, 0, 0, 0);
            acc = __builtin_amdgcn_mfma_f32_16x16x32_bf16(t1, b1, acc, 0, 0, 0);
            float bia = smemF[B2F + rw];
            #pragma unroll
            for (int j = 0; j < 4; ++j) {
                float xu = bf2f(u < 8 ? xr0[j][u] : xr1[j][u - 8]);
                o0[j] = fmaf(xu, acc[j] + bia, o0[j]);
            }
        }
        const int s2 = c >> 2;
        #pragma unroll
        for (int f = 0; f < 4; ++f) {
            int rw = 256 + f * 16 + c;
            bf16x8 b0 = *(const bf16x8*)&smemS[W2O + rw * 48 + g * 8];
            int b1o = (g < 2) ? (W2O + rw * 48 + 32 + g * 8) : ZOFF;
            bf16x8 b1 = *(const bf16x8*)&smemS[b1o];
            f32x4 acc = {0.f, 0.f, 0.f, 0.f};
            acc = __builtin_amdgcn_mfma_f32_16x16x32_bf16(t0, b0, acc, 0, 0, 0);
            acc = __builtin_amdgcn_mfma_f32_16x16x32_bf16(t1, b1, acc, 0, 0, 0);
            float bia = smemF[B2F + rw];
            #pragma unroll
            for (int j = 0; j < 4; ++j) {
                float e0, e1, e2, e3;
                if (f < 2) {
                    e0 = bf2f(xr0[j][f*4+0]); e1 = bf2f(xr0[j][f*4+1]);
                    e2 = bf2f(xr0[j][f*4+2]); e3 = bf2f(xr0[j][f*4+3]);
                } else {
                    e0 = bf2f(xr1[j][(f-2)*4+0]); e1 = bf2f(xr1[j][(f-2)*4+1]);
                    e2 = bf2f(xr1[j][(f-2)*4+2]); e3 = bf2f(xr1[j][(f-2)*4+3]);
                }
                float xu = e0;
                xu = (s2 == 1) ? e1 : xu;
                xu = (s2 == 2) ? e2 : xu;
                xu = (s2 == 3) ? e3 : xu;
                o1[j] = fmaf(xu, acc[j] + bia, o1[j]);
            }
        }
        #pragma unroll
        for (int j = 0; j < 4; ++j) {
            o1[j] += __shfl_xor(o1[j], 4);
            o1[j] += __shfl_xor(o1[j], 8);
        }

        // ---- epilogue ----
        const float inv = 0.25f;
        #pragma unroll
        for (int j = 0; j < 4; ++j) {
            int e = ebase + g * 4 + j;
            float4 sv = *(const float4*)&smemF[SVB + (g*4 + j) * 4];
            int srcn = __float_as_int(sv.w);
            if constexpr (SLOT) {
                // line-aligned full-line message write: no RMW, no line sharing
                int pos = 0;
                if (c == j && e < E) pos = atomicAdd(cursor + srcn, 1);
                int slot = __shfl(pos, (g << 4) + j);
                // lane c<12 needs o1 for v=c/3 (held at lane g*16 + c/3)
                int lsrc = (g << 4) + (c < 12 ? c / 3 : 0);
                float ov = __shfl(o1[j], lsrc);
                int m3 = c - 3 * (c / 3);
                float shm = (m3 == 0) ? sv.x : ((m3 == 1) ? sv.y : sv.z);
                float v2 = (c < 12) ? ov * shm * inv : 0.f;
                if (e < E) {
                    float* mb = dst_buf + (size_t)slot * mstride;
                    mb[c] = o0[j] * inv;
                    if (c < 12 || pad32) mb[16 + c] = v2;
                }
            } else {
                if (e < E) {
                    float* ob = dst_buf + (size_t)srcn * 28;
                    atomicAdd(ob + c, o0[j] * inv);
                    if (c < 4) {
                        float qq = o1[j] * inv;
                        atomicAdd(ob + 16 + 3*c + 0, qq * sv.x);
                        atomicAdd(ob + 16 + 3*c + 1, qq * sv.y);
                        atomicAdd(ob + 16 + 3*c + 2, qq * sv.z);
                    }
                    if (c == 0) atomicAdd(cnt + srcn, 1.0f);
                }
            }
        }

        // ---- stage next tile into buf[p^1] + sX/sV ----
        if (haven) {
            if (nen >= E) {
                A0 = make_float4(0,0,0,0); A1 = A0; A2 = A0; X = A0;
                vx = vy = vz = 0.f; nsI = 0;
            }
            int b = SLW + (p ^ 1) * 768 + r * 48 + q * 12;
            *(short4*)&smemS[b + 0] = make_short4(f2bf(A0.x), f2bf(A0.y), f2bf(A0.z), f2bf(A0.w));
            *(short4*)&smemS[b + 4] = make_short4(f2bf(A1.x), f2bf(A1.y), f2bf(A1.z), f2bf(A1.w));
            *(short4*)&smemS[b + 8] = make_short4(f2bf(A2.x), f2bf(A2.y), f2bf(A2.z), f2bf(A2.w));
            *(short4*)&smemS[SXB + r * 16 + q * 4] =
                make_short4(f2bf(X.x), f2bf(X.y), f2bf(X.z), f2bf(X.w));
            if (q == 0) {
                float rn = 1.0f / (sqrtf(vx*vx + vy*vy + vz*vz) + 1e-8f);
                const float c1 = 1.7320508075688772f;
                float4 sv = make_float4(c1*vx*rn, c1*vy*rn, c1*vz*rn, __int_as_float(nsI));
                *(float4*)&smemF[SVB + r * 4] = sv;
            }
        }
        m = mn; have = haven; p ^= 1;
    }
}

__global__ __launch_bounds__(256) void hist_kernel(
    const int* __restrict__ edge_index, int* __restrict__ deg, int E)
{
    int i = blockIdx.x * blockDim.x + threadIdx.x;
    if (i < E) atomicAdd(deg + edge_index[i], 1);
}

__global__ __launch_bounds__(1024) void scan_kernel(
    const int* __restrict__ deg, int* __restrict__ starts,
    int* __restrict__ cursor, int N)
{
    __shared__ int lds[1024];
    int t = threadIdx.x;
    int chunk = (N + 1023) / 1024;
    int lo = t * chunk;
    int hi = lo + chunk; if (hi > N) hi = N;
    int s = 0;
    for (int i = lo; i < hi; ++i) s += deg[i];
    lds[t] = s;
    __syncthreads();
    int v = s;
    for (int off = 1; off < 1024; off <<= 1) {
        int u = (t >= off) ? lds[t - off] : 0;
        __syncthreads();
        v += u;
        lds[t] = v;
        __syncthreads();
    }
    int run = v - s;
    for (int i = lo; i < hi; ++i) {
        starts[i] = run;
        cursor[i] = run;
        run += deg[i];
    }
}

__global__ __launch_bounds__(256) void sum_kernel(
    const float* __restrict__ msg, const int* __restrict__ starts,
    const int* __restrict__ deg, float* __restrict__ out, int N, int mstride)
{
    int wvid = (blockIdx.x * blockDim.x + threadIdx.x) >> 5;
    int ch = threadIdx.x & 31;
    int n = wvid;
    if (n < N && ch < 28) {
        int s = starts[n];
        int d = deg[n];
        float acc = 0.f;
        for (int k = 0; k < d; ++k)
            acc += msg[(size_t)(s + k) * mstride + ch];
        out[(size_t)n * 28 + ch] = acc / fmaxf((float)d, 1.0f);
    }
}

__global__ __launch_bounds__(256) void finalize_kernel(
    float* __restrict__ out, const float* __restrict__ cnt, int total)
{
    int i = blockIdx.x * blockDim.x + threadIdx.x;
    if (i < total) {
        float cv = cnt[i / 28];
        out[i] = out[i] / fmaxf(cv, 1.0f);
    }
}

extern "C" void kernel_launch(void* const* d_in, const int* in_sizes, int n_in,
                              void* d_out, int out_size, void* d_ws, size_t ws_size,
                              hipStream_t stream) {
    const float* node_attr  = (const float*)d_in[0];
    const float* edge_attr  = (const float*)d_in[1];
    const float* edge_vec   = (const float*)d_in[2];
    const float* fc1_w      = (const float*)d_in[3];
    const float* fc1_b      = (const float*)d_in[4];
    const float* fc2_w      = (const float*)d_in[5];
    const float* fc2_b      = (const float*)d_in[6];
    const int*   edge_index = (const int*)d_in[7];

    int E = in_sizes[2] / 3;      // 400000
    int N = in_sizes[0] / NS;     // 50000
    float* out = (float*)d_out;
    int MT = (E + 15) / 16;

    size_t need32 = ((size_t)E * 32 + 3 * (size_t)N) * sizeof(float);
    size_t need28 = ((size_t)E * 28 + 3 * (size_t)N) * sizeof(float);
    int mstride = (ws_size >= need32) ? 32 : 28;

    if (ws_size >= need28) {
        float* msg  = (float*)d_ws;
        int* ip     = (int*)((char*)d_ws + (size_t)E * mstride * sizeof(float));
        int* deg    = ip;
        int* starts = ip + N;
        int* cursor = ip + 2 * N;

        hipMemsetAsync(deg, 0, (size_t)N * sizeof(int), stream);
        hist_kernel<<<(E + 255) / 256, 256, 0, stream>>>(edge_index, deg, E);
        scan_kernel<<<1, 1024, 0, stream>>>(deg, starts, cursor, N);
        edge_mfma_kernel<true><<<NBLK, 256, 0, stream>>>(
            node_attr, edge_attr, edge_vec, fc1_w, fc1_b, fc2_w, fc2_b,
            edge_index, msg, nullptr, cursor, E, MT, mstride, mstride == 32);
        sum_kernel<<<((size_t)N * 32 + 255) / 256, 256, 0, stream>>>(
            msg, starts, deg, out, N, mstride);
    } else {
        float* cnt = (float*)d_ws;
        hipMemsetAsync(d_out, 0, (size_t)out_size * sizeof(float), stream);
        hipMemsetAsync(d_ws, 0, (size_t)N * sizeof(float), stream);
        edge_mfma_kernel<false><<<NBLK, 256, 0, stream>>>(
            node_attr, edge_attr, edge_vec, fc1_w, fc1_b, fc2_w, fc2_b,
            edge_index, out, cnt, nullptr, E, MT, 28, 0);
        int total = N * 28;
        finalize_kernel<<<(total + 255) / 256, 256, 0, stream>>>(out, cnt, total);
    }
}

// Round 6
// 306.494 us; speedup vs baseline: 1.3740x; 1.2962x over previous
//
#include <hip/hip_runtime.h>
#include <hip/hip_bf16.h>
#include <math.h>

#define NS 16
#define H  48
#define TB 128            // edges per block-tile
#define THREADS 256       // 4 waves

typedef __attribute__((ext_vector_type(8))) short bf16x8;
typedef __attribute__((ext_vector_type(4))) float f32x4;

// ---- LDS layout (halfword offsets; stride 56 hw = 112 B -> 2-way banks, free) ----
#define W1O 0            // [48 n][56]  fc1^T
#define W2O 2688         // [320 n][56] fc2^T
#define ZO  20608        // 16B zero block
#define AO  20616        // [128][56] A bf16
#define TO  27784        // [128][56] T bf16
#define XO  34952        // [128][16] x bf16
#define B1F 18500        // float idx: fc1_b[48]
#define B2F 18548        // float idx: fc2_b[320]
#define SVF 18868        // float idx: [128][4] {shx,shy,shz,src-bits}
#define SLI 19380        // int idx: [128] slot
#define SMEM_HW 39016    // 78032 bytes -> 2 blocks/CU

__device__ __forceinline__ short f2bf(float f) {
    unsigned b = __float_as_uint(f);
    unsigned r = (b + 0x7FFFu + ((b >> 16) & 1u)) >> 16;
    return (short)r;
}
__device__ __forceinline__ float bf2f(short s) {
    return __uint_as_float(((unsigned)(unsigned short)s) << 16);
}

template<bool SLOT>
__global__ __launch_bounds__(THREADS, 2) void edge_mfma_kernel(
    const float* __restrict__ node_attr,
    const float* __restrict__ edge_attr,
    const float* __restrict__ edge_vec,
    const float* __restrict__ fc1_w,
    const float* __restrict__ fc1_b,
    const float* __restrict__ fc2_w,
    const float* __restrict__ fc2_b,
    const int*   __restrict__ edge_index,
    float* __restrict__ dst_buf,   // SLOT ? msg[E][32] : out[N][28]
    float* __restrict__ cnt,       // !SLOT only
    int*   __restrict__ cursor,    // SLOT only
    int E)
{
    __shared__ __align__(16) short smemS[SMEM_HW];
    float* smemF = (float*)smemS;
    int*   smemI = (int*)smemS;
    const int tid = threadIdx.x;
    const int base = blockIdx.x * TB;

    // ---- weights + biases (L2-hot; coalesced reads, scattered LDS writes) ----
    for (int idx = tid; idx < 48 * 48; idx += THREADS) {
        int j = idx / 48, n = idx % 48;
        smemS[W1O + n * 56 + j] = f2bf(fc1_w[idx]);
    }
    for (int idx = tid; idx < 48 * 320; idx += THREADS) {
        int j = idx / 320, n = idx % 320;
        smemS[W2O + n * 56 + j] = f2bf(fc2_w[idx]);
    }
    if (tid < 48) smemF[B1F + tid] = fc1_b[tid];
    for (int idx = tid; idx < 320; idx += THREADS) smemF[B2F + idx] = fc2_b[idx];
    if (tid < 8) smemS[ZO + tid] = 0;

    // ---- per-edge staging: 2 threads per edge ----
    {
        const int r = tid >> 1, h = tid & 1;
        const int e = base + r;
        const int ce = e < E ? e : (E - 1);
        const int dI = edge_index[E + ce];
        const float* ap = edge_attr + (size_t)ce * H + h * 24;
        float4 A0 = *(const float4*)(ap + 0);
        float4 A1 = *(const float4*)(ap + 4);
        float4 A2 = *(const float4*)(ap + 8);
        float4 A3 = *(const float4*)(ap + 12);
        float4 A4 = *(const float4*)(ap + 16);
        float4 A5 = *(const float4*)(ap + 20);
        const float* xp = node_attr + (size_t)dI * NS + h * 8;
        float4 X0 = *(const float4*)(xp + 0);
        float4 X1 = *(const float4*)(xp + 4);
        if (e >= E) {
            A0 = make_float4(0,0,0,0); A1 = A0; A2 = A0; A3 = A0; A4 = A0; A5 = A0;
            X0 = A0; X1 = A0;
        }
        const int ab = AO + r * 56 + h * 24;
        *(short4*)&smemS[ab + 0]  = make_short4(f2bf(A0.x), f2bf(A0.y), f2bf(A0.z), f2bf(A0.w));
        *(short4*)&smemS[ab + 4]  = make_short4(f2bf(A1.x), f2bf(A1.y), f2bf(A1.z), f2bf(A1.w));
        *(short4*)&smemS[ab + 8]  = make_short4(f2bf(A2.x), f2bf(A2.y), f2bf(A2.z), f2bf(A2.w));
        *(short4*)&smemS[ab + 12] = make_short4(f2bf(A3.x), f2bf(A3.y), f2bf(A3.z), f2bf(A3.w));
        *(short4*)&smemS[ab + 16] = make_short4(f2bf(A4.x), f2bf(A4.y), f2bf(A4.z), f2bf(A4.w));
        *(short4*)&smemS[ab + 20] = make_short4(f2bf(A5.x), f2bf(A5.y), f2bf(A5.z), f2bf(A5.w));
        *(short4*)&smemS[XO + r * 16 + h * 8 + 0] =
            make_short4(f2bf(X0.x), f2bf(X0.y), f2bf(X0.z), f2bf(X0.w));
        *(short4*)&smemS[XO + r * 16 + h * 8 + 4] =
            make_short4(f2bf(X1.x), f2bf(X1.y), f2bf(X1.z), f2bf(X1.w));
        if (h == 0) {
            int sI = edge_index[ce];
            float vx = 0.f, vy = 0.f, vz = 0.f;
            if (e < E) {
                vx = edge_vec[3 * (size_t)ce + 0];
                vy = edge_vec[3 * (size_t)ce + 1];
                vz = edge_vec[3 * (size_t)ce + 2];
            } else sI = 0;
            float rn = 1.0f / (sqrtf(vx*vx + vy*vy + vz*vz) + 1e-8f);
            const float c1 = 1.7320508075688772f;
            *(float4*)&smemF[SVF + r * 4] =
                make_float4(c1*vx*rn, c1*vy*rn, c1*vz*rn, __int_as_float(sI));
            if constexpr (SLOT) {
                int slot = 0;
                if (e < E) slot = atomicAdd(cursor + sI, 1);
                smemI[SLI + r] = slot;
            }
        }
    }
    __syncthreads();

    const int l  = tid & 63;
    const int wv = tid >> 6;   // 0..3, wave owns rows 32wv..32wv+31
    const int g  = l >> 4;
    const int c  = l & 15;
    const int rb = wv * 32;

    // ---- GEMM1: T = relu(A @ W1 + b1), two 16-row fragments per wave ----
    #pragma unroll
    for (int m = 0; m < 2; ++m) {
        const int rowA = rb + m * 16 + c;
        bf16x8 a0 = *(const bf16x8*)&smemS[AO + rowA * 56 + g * 8];
        bf16x8 a1 = *(const bf16x8*)&smemS[(g < 2) ? (AO + rowA * 56 + 32 + g * 8) : ZO];
        #pragma unroll
        for (int fr = 0; fr < 3; ++fr) {
            bf16x8 b0 = *(const bf16x8*)&smemS[W1O + (fr*16 + c) * 56 + g * 8];
            bf16x8 b1 = *(const bf16x8*)&smemS[(g < 2) ? (W1O + (fr*16 + c) * 56 + 32 + g * 8) : ZO];
            f32x4 acc = {0.f, 0.f, 0.f, 0.f};
            acc = __builtin_amdgcn_mfma_f32_16x16x32_bf16(a0, b0, acc, 0, 0, 0);
            acc = __builtin_amdgcn_mfma_f32_16x16x32_bf16(a1, b1, acc, 0, 0, 0);
            float bia = smemF[B1F + fr * 16 + c];
            #pragma unroll
            for (int j = 0; j < 4; ++j)
                smemS[TO + (rb + m*16 + g*4 + j) * 56 + fr * 16 + c] =
                    f2bf(fmaxf(acc[j] + bia, 0.f));
        }
    }

    // ---- fragments for GEMM2 (same-wave LDS write->read; compiler orders) ----
    bf16x8 tf0[2], tf1[2];
    #pragma unroll
    for (int m = 0; m < 2; ++m) {
        const int rowA = rb + m * 16 + c;
        tf0[m] = *(const bf16x8*)&smemS[TO + rowA * 56 + g * 8];
        tf1[m] = *(const bf16x8*)&smemS[(g < 2) ? (TO + rowA * 56 + 32 + g * 8) : ZO];
    }
    bf16x8 xr0[2][4], xr1[2][4];
    #pragma unroll
    for (int m = 0; m < 2; ++m)
        #pragma unroll
        for (int j = 0; j < 4; ++j) {
            const int row = rb + m*16 + g*4 + j;
            xr0[m][j] = *(const bf16x8*)&smemS[XO + row * 16];
            xr1[m][j] = *(const bf16x8*)&smemS[XO + row * 16 + 8];
        }

    // ---- GEMM2 + fused contraction with x ----
    float o0[2][4] = {{0.f,0.f,0.f,0.f},{0.f,0.f,0.f,0.f}};
    float o1[2][4] = {{0.f,0.f,0.f,0.f},{0.f,0.f,0.f,0.f}};
    #pragma unroll
    for (int u = 0; u < 16; ++u) {
        bf16x8 b0 = *(const bf16x8*)&smemS[W2O + (u*16 + c) * 56 + g * 8];
        bf16x8 b1 = *(const bf16x8*)&smemS[(g < 2) ? (W2O + (u*16 + c) * 56 + 32 + g * 8) : ZO];
        float bia = smemF[B2F + u * 16 + c];
        #pragma unroll
        for (int m = 0; m < 2; ++m) {
            f32x4 acc = {0.f, 0.f, 0.f, 0.f};
            acc = __builtin_amdgcn_mfma_f32_16x16x32_bf16(tf0[m], b0, acc, 0, 0, 0);
            acc = __builtin_amdgcn_mfma_f32_16x16x32_bf16(tf1[m], b1, acc, 0, 0, 0);
            #pragma unroll
            for (int j = 0; j < 4; ++j) {
                float xu = bf2f(u < 8 ? xr0[m][j][u] : xr1[m][j][u - 8]);
                o0[m][j] = fmaf(xu, acc[j] + bia, o0[m][j]);
            }
        }
    }
    const int s2 = c >> 2;
    #pragma unroll
    for (int f = 0; f < 4; ++f) {
        const int rw = 256 + f * 16 + c;
        bf16x8 b0 = *(const bf16x8*)&smemS[W2O + rw * 56 + g * 8];
        bf16x8 b1 = *(const bf16x8*)&smemS[(g < 2) ? (W2O + rw * 56 + 32 + g * 8) : ZO];
        float bia = smemF[B2F + rw];
        #pragma unroll
        for (int m = 0; m < 2; ++m) {
            f32x4 acc = {0.f, 0.f, 0.f, 0.f};
            acc = __builtin_amdgcn_mfma_f32_16x16x32_bf16(tf0[m], b0, acc, 0, 0, 0);
            acc = __builtin_amdgcn_mfma_f32_16x16x32_bf16(tf1[m], b1, acc, 0, 0, 0);
            #pragma unroll
            for (int j = 0; j < 4; ++j) {
                float e0, e1, e2, e3;
                if (f < 2) {
                    e0 = bf2f(xr0[m][j][f*4+0]); e1 = bf2f(xr0[m][j][f*4+1]);
                    e2 = bf2f(xr0[m][j][f*4+2]); e3 = bf2f(xr0[m][j][f*4+3]);
                } else {
                    e0 = bf2f(xr1[m][j][(f-2)*4+0]); e1 = bf2f(xr1[m][j][(f-2)*4+1]);
                    e2 = bf2f(xr1[m][j][(f-2)*4+2]); e3 = bf2f(xr1[m][j][(f-2)*4+3]);
                }
                float xu = e0;
                xu = (s2 == 1) ? e1 : xu;
                xu = (s2 == 2) ? e2 : xu;
                xu = (s2 == 3) ? e3 : xu;
                o1[m][j] = fmaf(xu, acc[j] + bia, o1[m][j]);
            }
        }
    }
    #pragma unroll
    for (int m = 0; m < 2; ++m)
        #pragma unroll
        for (int j = 0; j < 4; ++j) {
            o1[m][j] += __shfl_xor(o1[m][j], 4);
            o1[m][j] += __shfl_xor(o1[m][j], 8);
        }

    // ---- epilogue ----
    const float inv = 0.25f;
    #pragma unroll
    for (int m = 0; m < 2; ++m)
        #pragma unroll
        for (int j = 0; j < 4; ++j) {
            const int r = rb + m*16 + g*4 + j;
            const int e = base + r;
            float4 sv = *(const float4*)&smemF[SVF + r * 4];
            if constexpr (SLOT) {
                int slot = smemI[SLI + r];
                int lsrc = (g << 4) + (c < 12 ? c / 3 : 0);
                float ov = __shfl(o1[m][j], lsrc);
                int m3 = c - 3 * (c / 3);
                float shm = (m3 == 0) ? sv.x : ((m3 == 1) ? sv.y : sv.z);
                float v2 = (c < 12) ? ov * shm * inv : 0.f;
                if (e < E) {
                    float* mb = dst_buf + (size_t)slot * 32;
                    mb[c] = o0[m][j] * inv;
                    mb[16 + c] = v2;
                }
            } else {
                int srcn = __float_as_int(sv.w);
                if (e < E) {
                    float* ob = dst_buf + (size_t)srcn * 28;
                    atomicAdd(ob + c, o0[m][j] * inv);
                    if (c < 4) {
                        float qq = o1[m][j] * inv;
                        atomicAdd(ob + 16 + 3*c + 0, qq * sv.x);
                        atomicAdd(ob + 16 + 3*c + 1, qq * sv.y);
                        atomicAdd(ob + 16 + 3*c + 2, qq * sv.z);
                    }
                    if (c == 0) atomicAdd(cnt + srcn, 1.0f);
                }
            }
        }
}

__global__ __launch_bounds__(256) void hist_kernel(
    const int* __restrict__ edge_index, int* __restrict__ deg, int E)
{
    int i = blockIdx.x * blockDim.x + threadIdx.x;
    if (i < E) atomicAdd(deg + edge_index[i], 1);
}

__global__ __launch_bounds__(1024) void scan_kernel(
    const int* __restrict__ deg, int* __restrict__ starts,
    int* __restrict__ cursor, int N)
{
    __shared__ int lds[1024];
    int t = threadIdx.x;
    int chunk = (N + 1023) / 1024;
    int lo = t * chunk;
    int hi = lo + chunk; if (hi > N) hi = N;
    int s = 0;
    for (int i = lo; i < hi; ++i) s += deg[i];
    lds[t] = s;
    __syncthreads();
    int v = s;
    for (int off = 1; off < 1024; off <<= 1) {
        int u = (t >= off) ? lds[t - off] : 0;
        __syncthreads();
        v += u;
        lds[t] = v;
        __syncthreads();
    }
    int run = v - s;
    for (int i = lo; i < hi; ++i) {
        starts[i] = run;
        cursor[i] = run;
        run += deg[i];
    }
}

// one full wave per node; lanes 0-31 / 32-63 take alternating messages
__global__ __launch_bounds__(256) void sum_kernel(
    const float* __restrict__ msg, const int* __restrict__ starts,
    const int* __restrict__ deg, float* __restrict__ out, int N)
{
    int w = (blockIdx.x * blockDim.x + threadIdx.x) >> 6;
    int l = threadIdx.x & 63;
    int half = l >> 5, ch = l & 31;
    if (w >= N) return;
    int s = starts[w], d = deg[w];
    float acc = 0.f;
    for (int k = half; k < d; k += 2)
        acc += msg[(size_t)(s + k) * 32 + ch];
    acc += __shfl_xor(acc, 32);
    if (l < 28) out[(size_t)w * 28 + l] = acc / fmaxf((float)d, 1.0f);
}

__global__ __launch_bounds__(256) void finalize_kernel(
    float* __restrict__ out, const float* __restrict__ cnt, int total)
{
    int i = blockIdx.x * blockDim.x + threadIdx.x;
    if (i < total) {
        float cv = cnt[i / 28];
        out[i] = out[i] / fmaxf(cv, 1.0f);
    }
}

extern "C" void kernel_launch(void* const* d_in, const int* in_sizes, int n_in,
                              void* d_out, int out_size, void* d_ws, size_t ws_size,
                              hipStream_t stream) {
    const float* node_attr  = (const float*)d_in[0];
    const float* edge_attr  = (const float*)d_in[1];
    const float* edge_vec   = (const float*)d_in[2];
    const float* fc1_w      = (const float*)d_in[3];
    const float* fc1_b      = (const float*)d_in[4];
    const float* fc2_w      = (const float*)d_in[5];
    const float* fc2_b      = (const float*)d_in[6];
    const int*   edge_index = (const int*)d_in[7];

    int E = in_sizes[2] / 3;      // 400000
    int N = in_sizes[0] / NS;     // 50000
    float* out = (float*)d_out;
    int nblk = (E + TB - 1) / TB; // 3125

    size_t need = ((size_t)E * 32 + 3 * (size_t)N) * sizeof(float);
    if (ws_size >= need) {
        float* msg  = (float*)d_ws;
        int* ip     = (int*)((char*)d_ws + (size_t)E * 32 * sizeof(float));
        int* deg    = ip;
        int* starts = ip + N;
        int* cursor = ip + 2 * N;

        hipMemsetAsync(deg, 0, (size_t)N * sizeof(int), stream);
        hist_kernel<<<(E + 255) / 256, 256, 0, stream>>>(edge_index, deg, E);
        scan_kernel<<<1, 1024, 0, stream>>>(deg, starts, cursor, N);
        edge_mfma_kernel<true><<<nblk, THREADS, 0, stream>>>(
            node_attr, edge_attr, edge_vec, fc1_w, fc1_b, fc2_w, fc2_b,
            edge_index, msg, nullptr, cursor, E);
        sum_kernel<<<((size_t)N * 64 + 255) / 256, 256, 0, stream>>>(
            msg, starts, deg, out, N);
    } else {
        float* cnt = (float*)d_ws;
        hipMemsetAsync(d_out, 0, (size_t)out_size * sizeof(float), stream);
        hipMemsetAsync(d_ws, 0, (size_t)N * sizeof(float), stream);
        edge_mfma_kernel<false><<<nblk, THREADS, 0, stream>>>(
            node_attr, edge_attr, edge_vec, fc1_w, fc1_b, fc2_w, fc2_b,
            edge_index, out, cnt, nullptr, E);
        int total = N * 28;
        finalize_kernel<<<(total + 255) / 256, 256, 0, stream>>>(out, cnt, total);
    }
}